// Round 1
// baseline (1343.184 us; speedup 1.0000x reference)
//
#include <hip/hip_runtime.h>
#include <hip/hip_bf16.h>
#include <math.h>

#define D_MODEL   512
#define N_LAYERS  3
#define D_INNER   1024
#define DT_RANK   32
#define D_STATE   16
#define D_CONV    4
#define RMS_EPS   1e-5f
#define B_SZ      2
#define L_SEQ     1024
#define NTOK      (B_SZ * L_SEQ)   // 2048

typedef __bf16 bf16_t;
typedef bf16_t bf16x8 __attribute__((ext_vector_type(8)));
typedef float  f32x4  __attribute__((ext_vector_type(4)));

// ---------------------------------------------------------------------------
// f32 -> bf16 convert (grid-stride)
// ---------------------------------------------------------------------------
__global__ __launch_bounds__(256) void cvt_f32_bf16(const float* __restrict__ src,
                                                    bf16_t* __restrict__ dst, int n) {
    int i = blockIdx.x * 256 + threadIdx.x;
    int stride = gridDim.x * 256;
    for (; i < n; i += stride) dst[i] = (bf16_t)src[i];
}

// ---------------------------------------------------------------------------
// RMSNorm: one wave per token (512 elems, 8/lane), writes bf16 u
// ---------------------------------------------------------------------------
__global__ __launch_bounds__(256) void rmsnorm_kernel(const float* __restrict__ x,
                                                      const float* __restrict__ w,
                                                      bf16_t* __restrict__ u) {
    int wid  = threadIdx.x >> 6;
    int lane = threadIdx.x & 63;
    int token = blockIdx.x * 4 + wid;
    const float* xr = x + (size_t)token * D_MODEL;
    f32x4 v0 = *(const f32x4*)&xr[lane * 8];
    f32x4 v1 = *(const f32x4*)&xr[lane * 8 + 4];
    float ss = 0.f;
#pragma unroll
    for (int i = 0; i < 4; i++) ss += v0[i] * v0[i] + v1[i] * v1[i];
#pragma unroll
    for (int m = 32; m >= 1; m >>= 1) ss += __shfl_xor(ss, m, 64);
    float scale = rsqrtf(ss * (1.0f / D_MODEL) + RMS_EPS);
    f32x4 w0 = *(const f32x4*)&w[lane * 8];
    f32x4 w1 = *(const f32x4*)&w[lane * 8 + 4];
    bf16_t* ur = u + (size_t)token * D_MODEL + lane * 8;
#pragma unroll
    for (int i = 0; i < 4; i++) {
        ur[i]     = (bf16_t)(v0[i] * scale * w0[i]);
        ur[i + 4] = (bf16_t)(v1[i] * scale * w1[i]);
    }
}

// ---------------------------------------------------------------------------
// Generic bf16 MFMA GEMM:  out[M][N] = A[M][K] * W[N][K]^T  (+ epilogue)
// 64x64 tile, BK=32, 4 waves, each wave 32x32 via 2x2 of 16x16x32 frags.
// EPI: 0=f32 store, 1=bf16 store, 2=x_proj(f32 store + bf16 copy of col<32),
//      3=softplus(acc+bias) f32 store, 4=f32 accumulate (residual)
// ---------------------------------------------------------------------------
template <int EPI>
__global__ __launch_bounds__(256) void gemm_bf16(const bf16_t* __restrict__ A,
                                                 const bf16_t* __restrict__ W,
                                                 float* __restrict__ outf,
                                                 bf16_t* __restrict__ outb,
                                                 const float* __restrict__ bias,
                                                 int M, int N, int K) {
    __shared__ bf16_t As[64][40];   // +8 pad: 80B row stride
    __shared__ bf16_t Bs[64][40];
    int tid = threadIdx.x;
    int m0 = blockIdx.y * 64, n0 = blockIdx.x * 64;
    int wid = tid >> 6, lane = tid & 63;
    int wm = (wid >> 1) * 32, wn = (wid & 1) * 32;
    int lr = lane & 15, kg = lane >> 4;

    f32x4 acc[2][2] = {};

    int srow = tid >> 2, scol = (tid & 3) * 8;
    const bf16_t* Ap = A + (size_t)(m0 + srow) * K + scol;
    const bf16_t* Wp = W + (size_t)(n0 + srow) * K + scol;

    for (int k0 = 0; k0 < K; k0 += 32) {
        *(bf16x8*)&As[srow][scol] = *(const bf16x8*)(Ap + k0);
        *(bf16x8*)&Bs[srow][scol] = *(const bf16x8*)(Wp + k0);
        __syncthreads();
        bf16x8 a0 = *(const bf16x8*)&As[wm + lr][kg * 8];
        bf16x8 a1 = *(const bf16x8*)&As[wm + 16 + lr][kg * 8];
        bf16x8 b0 = *(const bf16x8*)&Bs[wn + lr][kg * 8];
        bf16x8 b1 = *(const bf16x8*)&Bs[wn + 16 + lr][kg * 8];
        acc[0][0] = __builtin_amdgcn_mfma_f32_16x16x32_bf16(a0, b0, acc[0][0], 0, 0, 0);
        acc[0][1] = __builtin_amdgcn_mfma_f32_16x16x32_bf16(a0, b1, acc[0][1], 0, 0, 0);
        acc[1][0] = __builtin_amdgcn_mfma_f32_16x16x32_bf16(a1, b0, acc[1][0], 0, 0, 0);
        acc[1][1] = __builtin_amdgcn_mfma_f32_16x16x32_bf16(a1, b1, acc[1][1], 0, 0, 0);
        __syncthreads();
    }

    int colb = lane & 15, rowb = (lane >> 4) * 4;
#pragma unroll
    for (int fm = 0; fm < 2; fm++)
#pragma unroll
        for (int fn = 0; fn < 2; fn++)
#pragma unroll
            for (int r = 0; r < 4; r++) {
                int row = m0 + wm + fm * 16 + rowb + r;
                int col = n0 + wn + fn * 16 + colb;
                float v = acc[fm][fn][r];
                size_t idx = (size_t)row * N + col;
                if (EPI == 0) {
                    outf[idx] = v;
                } else if (EPI == 1) {
                    outb[idx] = (bf16_t)v;
                } else if (EPI == 2) {
                    outf[idx] = v;
                    if (col < DT_RANK) outb[(size_t)row * DT_RANK + col] = (bf16_t)v;
                } else if (EPI == 3) {
                    float t = v + bias[col];
                    outf[idx] = (t > 15.f) ? t : log1pf(__expf(t));
                } else if (EPI == 4) {
                    outf[idx] += v;
                }
            }
}

// ---------------------------------------------------------------------------
// Depthwise causal conv (k=4) + bias + silu, reads x-half of xz (bf16),
// writes bf16 xc. One thread per (b,l,e).
// ---------------------------------------------------------------------------
__global__ __launch_bounds__(256) void conv_silu_kernel(const bf16_t* __restrict__ xz,
                                                        const float* __restrict__ cw,
                                                        const float* __restrict__ cb,
                                                        bf16_t* __restrict__ xc) {
    int idx = blockIdx.x * 256 + threadIdx.x;   // (b*L + l)*D_INNER + e
    int e = idx & (D_INNER - 1);
    int t = idx >> 10;                          // token = b*L + l
    int l = t & (L_SEQ - 1);
    const bf16_t* xp = xz + (size_t)t * (2 * D_INNER) + e;
    float w0 = cw[e * 4], w1 = cw[e * 4 + 1], w2 = cw[e * 4 + 2], w3 = cw[e * 4 + 3];
    float acc = cb[e];
    if (l >= 3) acc += w0 * (float)xp[-3 * 2 * D_INNER];
    if (l >= 2) acc += w1 * (float)xp[-2 * 2 * D_INNER];
    if (l >= 1) acc += w2 * (float)xp[-1 * 2 * D_INNER];
    acc += w3 * (float)xp[0];
    float s = acc / (1.f + __expf(-acc));       // silu
    xc[idx] = (bf16_t)s;
}

// ---------------------------------------------------------------------------
// Fused selective scan. Thread = (b, e, n): n = tid&15, e-local = tid>>4.
// Block = 16 e-channels x 16 states. Grid = B * (D_INNER/16) = 128.
// Epilogue fuses  y = (sum_n h*C + D*x) * silu(z)  -> bf16 yz.
// ---------------------------------------------------------------------------
__global__ __launch_bounds__(256) void scan_kernel(const float* __restrict__ delta,
                                                   const bf16_t* __restrict__ xc,
                                                   const float* __restrict__ dbc,
                                                   const bf16_t* __restrict__ xz,
                                                   const float* __restrict__ A_log,
                                                   const float* __restrict__ Dskip,
                                                   bf16_t* __restrict__ yz) {
    int n  = threadIdx.x & 15;
    int el = threadIdx.x >> 4;
    int b  = blockIdx.x >> 6;
    int e  = (blockIdx.x & 63) * 16 + el;

    float Aa = -__expf(A_log[e * D_STATE + n]);
    float Dv = Dskip[e];
    float h = 0.f;
    size_t base = (size_t)b * L_SEQ;

    // prefetch l = 0
    float dv = delta[base * D_INNER + e];
    float xv = (float)xc[base * D_INNER + e];
    float Bv = dbc[base * 64 + DT_RANK + n];
    float Cv = dbc[base * 64 + DT_RANK + D_STATE + n];
    float zv = (float)xz[base * (2 * D_INNER) + D_INNER + e];

    for (int l = 0; l < L_SEQ; ++l) {
        float dv2 = 0.f, xv2 = 0.f, Bv2 = 0.f, Cv2 = 0.f, zv2 = 0.f;
        if (l + 1 < L_SEQ) {
            size_t tn = base + l + 1;
            dv2 = delta[tn * D_INNER + e];
            xv2 = (float)xc[tn * D_INNER + e];
            Bv2 = dbc[tn * 64 + DT_RANK + n];
            Cv2 = dbc[tn * 64 + DT_RANK + D_STATE + n];
            zv2 = (float)xz[tn * (2 * D_INNER) + D_INNER + e];
        }
        float dA = __expf(dv * Aa);
        h = dA * h + (dv * xv) * Bv;
        float p = h * Cv;
        p += __shfl_xor(p, 1, 16);
        p += __shfl_xor(p, 2, 16);
        p += __shfl_xor(p, 4, 16);
        p += __shfl_xor(p, 8, 16);
        if (n == 0) {
            float y = (p + Dv * xv) * (zv / (1.f + __expf(-zv)));
            yz[(base + l) * D_INNER + e] = (bf16_t)y;
        }
        dv = dv2; xv = xv2; Bv = Bv2; Cv = Cv2; zv = zv2;
    }
}

// ---------------------------------------------------------------------------
extern "C" void kernel_launch(void* const* d_in, const int* in_sizes, int n_in,
                              void* d_out, int out_size, void* d_ws, size_t ws_size,
                              hipStream_t stream) {
    const float* x_in  = (const float*)d_in[0];
    const float* ipw   = (const float*)d_in[1];
    const float* cw    = (const float*)d_in[2];
    const float* cb    = (const float*)d_in[3];
    const float* xpw   = (const float*)d_in[4];
    const float* dtw   = (const float*)d_in[5];
    const float* dtb   = (const float*)d_in[6];
    const float* A_log = (const float*)d_in[7];
    const float* Dsk   = (const float*)d_in[8];
    const float* opw   = (const float*)d_in[9];
    const float* nw    = (const float*)d_in[10];
    float* out = (float*)d_out;

    char* ws = (char*)d_ws;
    size_t off = 0;
    auto alloc = [&](size_t bytes) -> void* {
        void* p = ws + off;
        off += (bytes + 255) & ~(size_t)255;
        return p;
    };
    bf16_t* wip    = (bf16_t*)alloc((size_t)N_LAYERS * 2 * D_INNER * D_MODEL * 2);
    bf16_t* wxp    = (bf16_t*)alloc((size_t)N_LAYERS * 64 * D_INNER * 2);
    bf16_t* wdt    = (bf16_t*)alloc((size_t)N_LAYERS * D_INNER * DT_RANK * 2);
    bf16_t* wop    = (bf16_t*)alloc((size_t)N_LAYERS * D_MODEL * D_INNER * 2);
    bf16_t* u_bf   = (bf16_t*)alloc((size_t)NTOK * D_MODEL * 2);
    bf16_t* xz_bf  = (bf16_t*)alloc((size_t)NTOK * 2 * D_INNER * 2);
    bf16_t* xc_bf  = (bf16_t*)alloc((size_t)NTOK * D_INNER * 2);
    float*  dbc    = (float*)alloc((size_t)NTOK * 64 * 4);
    bf16_t* din_bf = (bf16_t*)alloc((size_t)NTOK * DT_RANK * 2);
    float*  deltaf = (float*)alloc((size_t)NTOK * D_INNER * 4);
    bf16_t* yz_bf  = (bf16_t*)alloc((size_t)NTOK * D_INNER * 2);

    // residual stream lives in d_out
    hipMemcpyAsync(out, x_in, (size_t)NTOK * D_MODEL * sizeof(float),
                   hipMemcpyDeviceToDevice, stream);

    // weight conversions (all layers at once)
    {
        int n1 = N_LAYERS * 2 * D_INNER * D_MODEL;
        int n2 = N_LAYERS * 64 * D_INNER;
        int n3 = N_LAYERS * D_INNER * DT_RANK;
        int n4 = N_LAYERS * D_MODEL * D_INNER;
        cvt_f32_bf16<<<2048, 256, 0, stream>>>(ipw, wip, n1);
        cvt_f32_bf16<<<512, 256, 0, stream>>>(xpw, wxp, n2);
        cvt_f32_bf16<<<256, 256, 0, stream>>>(dtw, wdt, n3);
        cvt_f32_bf16<<<1024, 256, 0, stream>>>(opw, wop, n4);
    }

    for (int l = 0; l < N_LAYERS; ++l) {
        // 1) u = rmsnorm(x) -> bf16
        rmsnorm_kernel<<<NTOK / 4, 256, 0, stream>>>(out, nw + l * D_MODEL, u_bf);
        // 2) xz = u @ ipw^T   (M=2048, N=2048, K=512) -> bf16
        gemm_bf16<1><<<dim3(2 * D_INNER / 64, NTOK / 64), 256, 0, stream>>>(
            u_bf, wip + (size_t)l * 2 * D_INNER * D_MODEL, nullptr, xz_bf, nullptr,
            NTOK, 2 * D_INNER, D_MODEL);
        // 3) xc = silu(conv(x) + b) -> bf16
        conv_silu_kernel<<<NTOK * D_INNER / 256, 256, 0, stream>>>(
            xz_bf, cw + (size_t)l * D_INNER * D_CONV, cb + (size_t)l * D_INNER, xc_bf);
        // 4) dbc = xc @ xpw^T (M=2048, N=64, K=1024) -> f32 + bf16 delta-part
        gemm_bf16<2><<<dim3(1, NTOK / 64), 256, 0, stream>>>(
            xc_bf, wxp + (size_t)l * 64 * D_INNER, dbc, din_bf, nullptr,
            NTOK, 64, D_INNER);
        // 5) delta = softplus(din @ dtw^T + dtb) (M=2048, N=1024, K=32) -> f32
        gemm_bf16<3><<<dim3(D_INNER / 64, NTOK / 64), 256, 0, stream>>>(
            din_bf, wdt + (size_t)l * D_INNER * DT_RANK, deltaf, nullptr,
            dtb + (size_t)l * D_INNER, NTOK, D_INNER, DT_RANK);
        // 6) selective scan + D*x + *silu(z) -> bf16 yz
        scan_kernel<<<B_SZ * (D_INNER / 16), 256, 0, stream>>>(
            deltaf, xc_bf, dbc, xz_bf, A_log + (size_t)l * D_INNER * D_STATE,
            Dsk + (size_t)l * D_INNER, yz_bf);
        // 7) x += yz @ opw^T (M=2048, N=512, K=1024) -> accumulate into d_out
        gemm_bf16<4><<<dim3(D_MODEL / 64, NTOK / 64), 256, 0, stream>>>(
            yz_bf, wop + (size_t)l * D_MODEL * D_INNER, out, nullptr, nullptr,
            NTOK, D_MODEL, D_INNER);
    }
}

// Round 2
// 371.492 us; speedup vs baseline: 3.6157x; 3.6157x over previous
//
#include <hip/hip_runtime.h>
#include <hip/hip_bf16.h>
#include <math.h>

#define D_MODEL   512
#define N_LAYERS  3
#define D_INNER   1024
#define DT_RANK   32
#define D_STATE   16
#define D_CONV    4
#define RMS_EPS   1e-5f
#define B_SZ      2
#define L_SEQ     1024
#define NTOK      (B_SZ * L_SEQ)   // 2048

typedef __bf16 bf16_t;
typedef bf16_t bf16x8 __attribute__((ext_vector_type(8)));
typedef float  f32x4  __attribute__((ext_vector_type(4)));

// ---------------------------------------------------------------------------
// f32 -> bf16 convert (grid-stride)
// ---------------------------------------------------------------------------
__global__ __launch_bounds__(256) void cvt_f32_bf16(const float* __restrict__ src,
                                                    bf16_t* __restrict__ dst, int n) {
    int i = blockIdx.x * 256 + threadIdx.x;
    int stride = gridDim.x * 256;
    for (; i < n; i += stride) dst[i] = (bf16_t)src[i];
}

// ---------------------------------------------------------------------------
// RMSNorm: one wave per token (512 elems, 8/lane), writes bf16 u
// ---------------------------------------------------------------------------
__global__ __launch_bounds__(256) void rmsnorm_kernel(const float* __restrict__ x,
                                                      const float* __restrict__ w,
                                                      bf16_t* __restrict__ u) {
    int wid  = threadIdx.x >> 6;
    int lane = threadIdx.x & 63;
    int token = blockIdx.x * 4 + wid;
    const float* xr = x + (size_t)token * D_MODEL;
    f32x4 v0 = *(const f32x4*)&xr[lane * 8];
    f32x4 v1 = *(const f32x4*)&xr[lane * 8 + 4];
    float ss = 0.f;
#pragma unroll
    for (int i = 0; i < 4; i++) ss += v0[i] * v0[i] + v1[i] * v1[i];
#pragma unroll
    for (int m = 32; m >= 1; m >>= 1) ss += __shfl_xor(ss, m, 64);
    float scale = rsqrtf(ss * (1.0f / D_MODEL) + RMS_EPS);
    f32x4 w0 = *(const f32x4*)&w[lane * 8];
    f32x4 w1 = *(const f32x4*)&w[lane * 8 + 4];
    bf16_t* ur = u + (size_t)token * D_MODEL + lane * 8;
#pragma unroll
    for (int i = 0; i < 4; i++) {
        ur[i]     = (bf16_t)(v0[i] * scale * w0[i]);
        ur[i + 4] = (bf16_t)(v1[i] * scale * w1[i]);
    }
}

// ---------------------------------------------------------------------------
// Generic bf16 MFMA GEMM:  out[M][N] = A[M][K] * W[N][K]^T  (+ epilogue)
// 64x64 tile, BK=32, 4 waves, each wave 32x32 via 2x2 of 16x16x32 frags.
// EPI: 0=f32 store, 1=bf16 store, 2=x_proj(f32 store + bf16 copy of col<32),
//      3=softplus(acc+bias) f32 store, 4=f32 accumulate (residual)
// ---------------------------------------------------------------------------
template <int EPI>
__global__ __launch_bounds__(256) void gemm_bf16(const bf16_t* __restrict__ A,
                                                 const bf16_t* __restrict__ W,
                                                 float* __restrict__ outf,
                                                 bf16_t* __restrict__ outb,
                                                 const float* __restrict__ bias,
                                                 int M, int N, int K) {
    __shared__ bf16_t As[64][40];   // +8 pad: 80B row stride
    __shared__ bf16_t Bs[64][40];
    int tid = threadIdx.x;
    int m0 = blockIdx.y * 64, n0 = blockIdx.x * 64;
    int wid = tid >> 6, lane = tid & 63;
    int wm = (wid >> 1) * 32, wn = (wid & 1) * 32;
    int lr = lane & 15, kg = lane >> 4;

    f32x4 acc[2][2] = {};

    int srow = tid >> 2, scol = (tid & 3) * 8;
    const bf16_t* Ap = A + (size_t)(m0 + srow) * K + scol;
    const bf16_t* Wp = W + (size_t)(n0 + srow) * K + scol;

    for (int k0 = 0; k0 < K; k0 += 32) {
        *(bf16x8*)&As[srow][scol] = *(const bf16x8*)(Ap + k0);
        *(bf16x8*)&Bs[srow][scol] = *(const bf16x8*)(Wp + k0);
        __syncthreads();
        bf16x8 a0 = *(const bf16x8*)&As[wm + lr][kg * 8];
        bf16x8 a1 = *(const bf16x8*)&As[wm + 16 + lr][kg * 8];
        bf16x8 b0 = *(const bf16x8*)&Bs[wn + lr][kg * 8];
        bf16x8 b1 = *(const bf16x8*)&Bs[wn + 16 + lr][kg * 8];
        acc[0][0] = __builtin_amdgcn_mfma_f32_16x16x32_bf16(a0, b0, acc[0][0], 0, 0, 0);
        acc[0][1] = __builtin_amdgcn_mfma_f32_16x16x32_bf16(a0, b1, acc[0][1], 0, 0, 0);
        acc[1][0] = __builtin_amdgcn_mfma_f32_16x16x32_bf16(a1, b0, acc[1][0], 0, 0, 0);
        acc[1][1] = __builtin_amdgcn_mfma_f32_16x16x32_bf16(a1, b1, acc[1][1], 0, 0, 0);
        __syncthreads();
    }

    int colb = lane & 15, rowb = (lane >> 4) * 4;
#pragma unroll
    for (int fm = 0; fm < 2; fm++)
#pragma unroll
        for (int fn = 0; fn < 2; fn++)
#pragma unroll
            for (int r = 0; r < 4; r++) {
                int row = m0 + wm + fm * 16 + rowb + r;
                int col = n0 + wn + fn * 16 + colb;
                float v = acc[fm][fn][r];
                size_t idx = (size_t)row * N + col;
                if (EPI == 0) {
                    outf[idx] = v;
                } else if (EPI == 1) {
                    outb[idx] = (bf16_t)v;
                } else if (EPI == 2) {
                    outf[idx] = v;
                    if (col < DT_RANK) outb[(size_t)row * DT_RANK + col] = (bf16_t)v;
                } else if (EPI == 3) {
                    float t = v + bias[col];
                    outf[idx] = (t > 15.f) ? t : log1pf(__expf(t));
                } else if (EPI == 4) {
                    outf[idx] += v;
                }
            }
}

// ---------------------------------------------------------------------------
// Depthwise causal conv (k=4) + bias + silu, reads x-half of xz (bf16),
// writes bf16 xc. One thread per (b,l,e).
// ---------------------------------------------------------------------------
__global__ __launch_bounds__(256) void conv_silu_kernel(const bf16_t* __restrict__ xz,
                                                        const float* __restrict__ cw,
                                                        const float* __restrict__ cb,
                                                        bf16_t* __restrict__ xc) {
    int idx = blockIdx.x * 256 + threadIdx.x;   // (b*L + l)*D_INNER + e
    int e = idx & (D_INNER - 1);
    int t = idx >> 10;                          // token = b*L + l
    int l = t & (L_SEQ - 1);
    const bf16_t* xp = xz + (size_t)t * (2 * D_INNER) + e;
    float w0 = cw[e * 4], w1 = cw[e * 4 + 1], w2 = cw[e * 4 + 2], w3 = cw[e * 4 + 3];
    float acc = cb[e];
    if (l >= 3) acc += w0 * (float)xp[-3 * 2 * D_INNER];
    if (l >= 2) acc += w1 * (float)xp[-2 * 2 * D_INNER];
    if (l >= 1) acc += w2 * (float)xp[-1 * 2 * D_INNER];
    acc += w3 * (float)xp[0];
    float s = acc / (1.f + __expf(-acc));       // silu
    xc[idx] = (bf16_t)s;
}

// ---------------------------------------------------------------------------
// Chunked selective scan, pass 1: per (b, e, chunk) thread computes the
// chunk-local scan (h from 0) keeping all 16 states in registers.
// Stores decay product P[16] and final h[16] into cs:
//   cs[((b*nc + c)*32 + j) * D_INNER + e],  j<16: P (later h_init), j>=16: h_fin
// Grid: (D_INNER/256, nc, B). B rows staged in LDS (broadcast reads).
// ---------------------------------------------------------------------------
__global__ __launch_bounds__(256) void scan_part1(const float* __restrict__ delta,
                                                  const bf16_t* __restrict__ xc,
                                                  const float* __restrict__ dbc,
                                                  const float* __restrict__ A_log,
                                                  float* __restrict__ cs, int nc) {
    int T = L_SEQ / nc;
    int e = blockIdx.x * 256 + threadIdx.x;
    int c = blockIdx.y;
    int b = blockIdx.z;
    size_t t0 = (size_t)b * L_SEQ + (size_t)c * T;

    __shared__ float Bs[32][16];   // T <= 32
    for (int i = threadIdx.x; i < T * 16; i += 256)
        Bs[i >> 4][i & 15] = dbc[(t0 + (i >> 4)) * 64 + DT_RANK + (i & 15)];
    __syncthreads();

    float Aa[16], h[16], P[16];
    const float* Ae = A_log + (size_t)e * D_STATE;
#pragma unroll
    for (int n = 0; n < 16; n++) { Aa[n] = -__expf(Ae[n]); h[n] = 0.f; P[n] = 1.f; }

    const float*  dp = delta + t0 * D_INNER + e;
    const bf16_t* xp = xc    + t0 * D_INNER + e;

    float dv = dp[0], xv = (float)xp[0];
    for (int l = 0; l < T; ++l) {
        float dv2 = 0.f, xv2 = 0.f;
        if (l + 1 < T) {
            dv2 = dp[(l + 1) * D_INNER];
            xv2 = (float)xp[(l + 1) * D_INNER];
        }
        float dx = dv * xv;
#pragma unroll
        for (int n = 0; n < 16; n++) {
            float dA = __expf(dv * Aa[n]);
            h[n] = dA * h[n] + dx * Bs[l][n];
            P[n] *= dA;
        }
        dv = dv2; xv = xv2;
    }

    float* o = cs + (size_t)(b * nc + c) * 32 * D_INNER + e;
#pragma unroll
    for (int n = 0; n < 16; n++) {
        o[n * D_INNER]        = P[n];
        o[(16 + n) * D_INNER] = h[n];
    }
}

// ---------------------------------------------------------------------------
// Pass 2: sequential combine over chunks per (b, e, n).
// Writes h_init for chunk c in-place over the P slot (read before overwrite).
// Grid: (D_INNER/256, D_STATE, B); fully coalesced over e.
// ---------------------------------------------------------------------------
__global__ __launch_bounds__(256) void scan_combine(float* __restrict__ cs, int nc) {
    int e = blockIdx.x * 256 + threadIdx.x;
    int n = blockIdx.y;
    int b = blockIdx.z;
    size_t stride = (size_t)32 * D_INNER;
    float* p = cs + ((size_t)b * nc * 32 + n) * D_INNER + e;

    float h = 0.f;
    float P = p[0], hf = p[16 * D_INNER];
    for (int c = 0; c < nc; ++c) {
        float P2 = 0.f, hf2 = 0.f;
        if (c + 1 < nc) {
            P2  = p[(c + 1) * stride];
            hf2 = p[(c + 1) * stride + 16 * D_INNER];
        }
        p[c * stride] = h;          // h_init for chunk c
        h = P * h + hf;
        P = P2; hf = hf2;
    }
}

// ---------------------------------------------------------------------------
// Pass 3: re-scan each chunk seeded with h_init; fuse
//   y = (sum_n h*C + D*x) * silu(z)  -> bf16 yz.
// ---------------------------------------------------------------------------
__global__ __launch_bounds__(256) void scan_part3(const float* __restrict__ delta,
                                                  const bf16_t* __restrict__ xc,
                                                  const float* __restrict__ dbc,
                                                  const bf16_t* __restrict__ xz,
                                                  const float* __restrict__ A_log,
                                                  const float* __restrict__ Dskip,
                                                  const float* __restrict__ cs,
                                                  bf16_t* __restrict__ yz, int nc) {
    int T = L_SEQ / nc;
    int e = blockIdx.x * 256 + threadIdx.x;
    int c = blockIdx.y;
    int b = blockIdx.z;
    size_t t0 = (size_t)b * L_SEQ + (size_t)c * T;

    __shared__ float BCs[32][32];  // col<16: B, col>=16: C
    for (int i = threadIdx.x; i < T * 32; i += 256)
        BCs[i >> 5][i & 31] = dbc[(t0 + (i >> 5)) * 64 + DT_RANK + (i & 31)];
    __syncthreads();

    float Aa[16], h[16];
    const float* Ae = A_log + (size_t)e * D_STATE;
    const float* hi = cs + (size_t)(b * nc + c) * 32 * D_INNER + e;
#pragma unroll
    for (int n = 0; n < 16; n++) {
        Aa[n] = -__expf(Ae[n]);
        h[n]  = hi[n * D_INNER];
    }
    float Dv = Dskip[e];

    const float*  dp = delta + t0 * D_INNER + e;
    const bf16_t* xp = xc    + t0 * D_INNER + e;
    const bf16_t* zp = xz    + t0 * 2 * D_INNER + D_INNER + e;
    bf16_t*       yp = yz    + t0 * D_INNER + e;

    float dv = dp[0], xv = (float)xp[0], zv = (float)zp[0];
    for (int l = 0; l < T; ++l) {
        float dv2 = 0.f, xv2 = 0.f, zv2 = 0.f;
        if (l + 1 < T) {
            dv2 = dp[(l + 1) * D_INNER];
            xv2 = (float)xp[(l + 1) * D_INNER];
            zv2 = (float)zp[(l + 1) * 2 * D_INNER];
        }
        float dx = dv * xv;
        float y  = Dv * xv;
#pragma unroll
        for (int n = 0; n < 16; n++) {
            float dA = __expf(dv * Aa[n]);
            h[n] = dA * h[n] + dx * BCs[l][n];
            y   += h[n] * BCs[l][16 + n];
        }
        yp[l * D_INNER] = (bf16_t)(y * (zv / (1.f + __expf(-zv))));
        dv = dv2; xv = xv2; zv = zv2;
    }
}

// ---------------------------------------------------------------------------
extern "C" void kernel_launch(void* const* d_in, const int* in_sizes, int n_in,
                              void* d_out, int out_size, void* d_ws, size_t ws_size,
                              hipStream_t stream) {
    const float* x_in  = (const float*)d_in[0];
    const float* ipw   = (const float*)d_in[1];
    const float* cw    = (const float*)d_in[2];
    const float* cb    = (const float*)d_in[3];
    const float* xpw   = (const float*)d_in[4];
    const float* dtw   = (const float*)d_in[5];
    const float* dtb   = (const float*)d_in[6];
    const float* A_log = (const float*)d_in[7];
    const float* Dsk   = (const float*)d_in[8];
    const float* opw   = (const float*)d_in[9];
    const float* nw    = (const float*)d_in[10];
    float* out = (float*)d_out;

    char* ws = (char*)d_ws;
    size_t off = 0;
    auto alloc = [&](size_t bytes) -> void* {
        void* p = ws + off;
        off += (bytes + 255) & ~(size_t)255;
        return p;
    };
    bf16_t* wip    = (bf16_t*)alloc((size_t)N_LAYERS * 2 * D_INNER * D_MODEL * 2);
    bf16_t* wxp    = (bf16_t*)alloc((size_t)N_LAYERS * 64 * D_INNER * 2);
    bf16_t* wdt    = (bf16_t*)alloc((size_t)N_LAYERS * D_INNER * DT_RANK * 2);
    bf16_t* wop    = (bf16_t*)alloc((size_t)N_LAYERS * D_MODEL * D_INNER * 2);
    bf16_t* u_bf   = (bf16_t*)alloc((size_t)NTOK * D_MODEL * 2);
    bf16_t* xz_bf  = (bf16_t*)alloc((size_t)NTOK * 2 * D_INNER * 2);
    bf16_t* xc_bf  = (bf16_t*)alloc((size_t)NTOK * D_INNER * 2);
    float*  dbc    = (float*)alloc((size_t)NTOK * 64 * 4);
    bf16_t* din_bf = (bf16_t*)alloc((size_t)NTOK * DT_RANK * 2);
    float*  deltaf = (float*)alloc((size_t)NTOK * D_INNER * 4);
    bf16_t* yz_bf  = (bf16_t*)alloc((size_t)NTOK * D_INNER * 2);

    // chunk state: [B][nc][32][D_INNER] f32. nc=64 -> 16.8 MB; fall back if tight.
    int nc = 64;
    if (off + (size_t)B_SZ * nc * 32 * D_INNER * 4 > ws_size) nc = 32;
    float* cstate = (float*)alloc((size_t)B_SZ * nc * 32 * D_INNER * 4);

    // residual stream lives in d_out
    hipMemcpyAsync(out, x_in, (size_t)NTOK * D_MODEL * sizeof(float),
                   hipMemcpyDeviceToDevice, stream);

    // weight conversions (all layers at once)
    {
        int n1 = N_LAYERS * 2 * D_INNER * D_MODEL;
        int n2 = N_LAYERS * 64 * D_INNER;
        int n3 = N_LAYERS * D_INNER * DT_RANK;
        int n4 = N_LAYERS * D_MODEL * D_INNER;
        cvt_f32_bf16<<<2048, 256, 0, stream>>>(ipw, wip, n1);
        cvt_f32_bf16<<<512, 256, 0, stream>>>(xpw, wxp, n2);
        cvt_f32_bf16<<<256, 256, 0, stream>>>(dtw, wdt, n3);
        cvt_f32_bf16<<<1024, 256, 0, stream>>>(opw, wop, n4);
    }

    for (int l = 0; l < N_LAYERS; ++l) {
        const float* Al = A_log + (size_t)l * D_INNER * D_STATE;
        // 1) u = rmsnorm(x) -> bf16
        rmsnorm_kernel<<<NTOK / 4, 256, 0, stream>>>(out, nw + l * D_MODEL, u_bf);
        // 2) xz = u @ ipw^T   (M=2048, N=2048, K=512) -> bf16
        gemm_bf16<1><<<dim3(2 * D_INNER / 64, NTOK / 64), 256, 0, stream>>>(
            u_bf, wip + (size_t)l * 2 * D_INNER * D_MODEL, nullptr, xz_bf, nullptr,
            NTOK, 2 * D_INNER, D_MODEL);
        // 3) xc = silu(conv(x) + b) -> bf16
        conv_silu_kernel<<<NTOK * D_INNER / 256, 256, 0, stream>>>(
            xz_bf, cw + (size_t)l * D_INNER * D_CONV, cb + (size_t)l * D_INNER, xc_bf);
        // 4) dbc = xc @ xpw^T (M=2048, N=64, K=1024) -> f32 + bf16 delta-part
        gemm_bf16<2><<<dim3(1, NTOK / 64), 256, 0, stream>>>(
            xc_bf, wxp + (size_t)l * 64 * D_INNER, dbc, din_bf, nullptr,
            NTOK, 64, D_INNER);
        // 5) delta = softplus(din @ dtw^T + dtb) (M=2048, N=1024, K=32) -> f32
        gemm_bf16<3><<<dim3(D_INNER / 64, NTOK / 64), 256, 0, stream>>>(
            din_bf, wdt + (size_t)l * D_INNER * DT_RANK, deltaf, nullptr,
            dtb + (size_t)l * D_INNER, NTOK, D_INNER, DT_RANK);
        // 6) chunked selective scan (+ D*x, *silu(z)) -> bf16 yz
        scan_part1<<<dim3(D_INNER / 256, nc, B_SZ), 256, 0, stream>>>(
            deltaf, xc_bf, dbc, Al, cstate, nc);
        scan_combine<<<dim3(D_INNER / 256, D_STATE, B_SZ), 256, 0, stream>>>(
            cstate, nc);
        scan_part3<<<dim3(D_INNER / 256, nc, B_SZ), 256, 0, stream>>>(
            deltaf, xc_bf, dbc, xz_bf, Al, Dsk + (size_t)l * D_INNER, cstate,
            yz_bf, nc);
        // 7) x += yz @ opw^T (M=2048, N=512, K=1024) -> accumulate into d_out
        gemm_bf16<4><<<dim3(D_MODEL / 64, NTOK / 64), 256, 0, stream>>>(
            yz_bf, wop + (size_t)l * D_MODEL * D_INNER, out, nullptr, nullptr,
            NTOK, D_MODEL, D_INNER);
    }
}